// Round 1
// baseline (296.580 us; speedup 1.0000x reference)
//
#include <hip/hip_runtime.h>
#include <math.h>

// AxialAttention on MI355X — round 6.
// K1/prep unchanged. K2 restructured: one block per (b, i-PAIR, g).
//  - kv (Phase B) and vl (Phase D) global loads shared across the 2 i's in
//    registers (halves L2 traffic per unit work; was ~18 TB/s = 52% of L2 ceiling).
//  - BN scales folded into staged LDS operands (qi' = sqk*q, qe' = (sqr/sqk)*q_rel,
//    ke' = skr*k_rel, ve' = (gsve/gsv)*v_rel): all 12 Phase-B fdot2 chain into ONE
//    accumulator initialized with the summed biases; Phase D chains sv+sve per ch.
//  - s16 (sim) aliases s32 (raw scores) with a mid-Phase-C barrier (scores held in
//    regs across it): LDS 34.5 KB -> 4 blocks/CU.
//  - Branchless Phase-B store (dup lanes rewrite w=55 with identical value).

typedef _Float16 f16;
typedef _Float16 f16x2 __attribute__((ext_vector_type(2)));
typedef _Float16 f16x4 __attribute__((ext_vector_type(4)));
typedef _Float16 f16x8 __attribute__((ext_vector_type(8)));
typedef float    f32x4 __attribute__((ext_vector_type(4)));
typedef unsigned int u32;
typedef unsigned int u32x2 __attribute__((ext_vector_type(2)));

static constexpr int NB    = 32;
static constexpr int HH    = 56;
static constexpr int CIN   = 128;
static constexpr int GG    = 8;
static constexpr int PLANE = HH * HH;     // 3136
static constexpr int MT    = 112;         // K1 M-tile (2 j-rows x 56 w)
static constexpr int NBLK  = 28;          // 3136 / 112

// -------------------------------------------------------------------------
// prep: Wt[d][k] f16, d in [0,256): 0-63 <- wq, 64-127 <- wk, 128-255 <- wv
// -------------------------------------------------------------------------
__global__ __launch_bounds__(256) void prep_kernel(
    const float* __restrict__ wq, const float* __restrict__ wk,
    const float* __restrict__ wv, f16* __restrict__ wt)
{
    const int id = blockIdx.x * 256 + threadIdx.x;   // 4096 total
    const int d = id >> 4, kc = id & 15;
    const float* src; int stride, dl;
    if (d < 64)       { src = wq; stride = 64;  dl = d; }
    else if (d < 128) { src = wk; stride = 64;  dl = d - 64; }
    else              { src = wv; stride = 128; dl = d - 128; }
    f16x8 v;
    #pragma unroll
    for (int kk = 0; kk < 8; ++kk)
        v[kk] = (f16)src[(kc * 8 + kk) * stride + dl];
    *(f16x8*)&wt[d * 128 + kc * 8] = v;
}

// -------------------------------------------------------------------------
// K1: block tile 112(M) x 128(N), K=128. Grid (896, 2): y=0 -> q|k, y=1 -> v.
// -------------------------------------------------------------------------
__global__ __launch_bounds__(256, 2) void qkv_kernel(
    const float* __restrict__ x, const f16* __restrict__ wt,
    const float* __restrict__ gq, const float* __restrict__ bq,
    const float* __restrict__ gk, const float* __restrict__ bk,
    const float* __restrict__ gv, const float* __restrict__ bv,
    f16* __restrict__ qt, f16* __restrict__ kt, f16* __restrict__ vt2)
{
    __shared__ f16 lds_a[MT * 136];     // A[m][k], later reused as C[m][d]
    __shared__ f16 lds_b[128 * 136];    // Bt[n][k]

    const int t    = threadIdx.x;
    const int nh   = blockIdx.y;
    const int b    = blockIdx.x / NBLK;
    const int B28  = blockIdx.x - b * NBLK;
    const int rem0 = B28 * MT;
    const size_t m0 = (size_t)b * PLANE + rem0;

    // ---- stage A: 112x128 f32 -> f16, coalesced float4 ----
    {
        const float4* xs = (const float4*)(x + m0 * CIN);
        #pragma unroll
        for (int it = 0; it < 14; ++it) {
            const int f = it * 256 + t;          // 3584 float4
            const int r = f >> 5, c = f & 31;
            const float4 v = xs[f];
            f16x4 p; p.x = (f16)v.x; p.y = (f16)v.y; p.z = (f16)v.z; p.w = (f16)v.w;
            *(f16x4*)&lds_a[r * 136 + c * 4] = p;
        }
    }
    // ---- stage B: pre-converted Wt, coalesced 16B ----
    #pragma unroll
    for (int it = 0; it < 8; ++it) {
        const int f = it * 256 + t;              // 2048 chunks
        const int n = f >> 4, kc = f & 15;
        *(f16x8*)&lds_b[n * 136 + kc * 8] =
            *(const f16x8*)&wt[(size_t)(nh * 128 + n) * 128 + kc * 8];
    }
    __syncthreads();

    const int lane = t & 63, wid = t >> 6;
    const int wn0 = wid * 32;
    const int ra = lane & 15, qd = lane >> 4;

    f32x4 acc[7][2];
    #pragma unroll
    for (int mt = 0; mt < 7; ++mt)
        #pragma unroll
        for (int nt = 0; nt < 2; ++nt)
            acc[mt][nt] = (f32x4){0.f, 0.f, 0.f, 0.f};

    #pragma unroll
    for (int ks = 0; ks < 4; ++ks) {
        f16x8 af[7], bf[2];
        #pragma unroll
        for (int mt = 0; mt < 7; ++mt)
            af[mt] = *(const f16x8*)&lds_a[(mt * 16 + ra) * 136 + ks * 32 + qd * 8];
        #pragma unroll
        for (int nt = 0; nt < 2; ++nt)
            bf[nt] = *(const f16x8*)&lds_b[(wn0 + nt * 16 + ra) * 136 + ks * 32 + qd * 8];
        #pragma unroll
        for (int mt = 0; mt < 7; ++mt)
            #pragma unroll
            for (int nt = 0; nt < 2; ++nt)
                acc[mt][nt] = __builtin_amdgcn_mfma_f32_16x16x32_f16(
                    af[mt], bf[nt], acc[mt][nt], 0, 0, 0);
    }
    __syncthreads();

    // ---- BN + f16, transpose via LDS (reuse lds_a as C[m][d]) ----
    f16* lds_c = lds_a;
    const float inv = 1.0f / sqrtf(1.001f);
    #pragma unroll
    for (int nt = 0; nt < 2; ++nt) {
        const int d  = wn0 + nt * 16 + ra;       // block-local col 0..127
        const int dg = nh * 128 + d;             // global col 0..255
        float scale, shift;
        if (dg < 64)       { scale = gq[dg] * inv;        shift = bq[dg]; }
        else if (dg < 128) { scale = gk[dg - 64] * inv;   shift = bk[dg - 64]; }
        else               { scale = gv[dg - 128] * inv;  shift = bv[dg - 128]; }
        #pragma unroll
        for (int mt = 0; mt < 7; ++mt)
            #pragma unroll
            for (int rg = 0; rg < 4; ++rg) {
                const int m = mt * 16 + qd * 4 + rg;
                lds_c[m * 136 + d] = (f16)fmaf(acc[mt][nt][rg], scale, shift);
            }
    }
    __syncthreads();

    if (nh == 0) {
        // q/k: 16B row stores, coalesced
        const int rl = t & 31, gs2 = t >> 5;
        #pragma unroll
        for (int it = 0; it < 4; ++it) {
            const int rem = it * 32 + rl;
            if (rem < MT) {
                #pragma unroll
                for (int half = 0; half < 2; ++half) {
                    const int gslot = half * 8 + gs2;
                    const f16x8 v = *(const f16x8*)&lds_c[rem * 136 + gslot * 8];
                    f16* dst = (gslot < 8) ? qt : kt;
                    const int g = gslot & 7;
                    *(f16x8*)&dst[((size_t)(b * GG + g) * PLANE + rem0 + rem) * 8] = v;
                }
            }
        }
    } else {
        // v -> vt2[bg][J=B28][w][c][jbit]: interleave rows w and w+56
        const int cq = t & 3, w8 = (t >> 2) & 7, g = t >> 5;
        #pragma unroll
        for (int it = 0; it < 7; ++it) {
            const int w = it * 8 + w8;
            const int doff = g * 16 + cq * 4;
            const u32x2 a  = *(const u32x2*)&lds_c[w * 136 + doff];         // j0: c0..c3
            const u32x2 bb = *(const u32x2*)&lds_c[(56 + w) * 136 + doff];  // j1: c0..c3
            uint4 o;
            o.x = __builtin_amdgcn_perm(a.x, bb.x, 0x01000504u);  // c0j0 c0j1
            o.y = __builtin_amdgcn_perm(a.x, bb.x, 0x03020706u);  // c1j0 c1j1
            o.z = __builtin_amdgcn_perm(a.y, bb.y, 0x01000504u);  // c2j0 c2j1
            o.w = __builtin_amdgcn_perm(a.y, bb.y, 0x03020706u);  // c3j0 c3j1
            const size_t base =
                (((size_t)(b * GG + g) * NBLK + B28) * HH + w) * 32 + cq * 8;
            *(uint4*)&vt2[base] = o;
        }
    }
}

// -------------------------------------------------------------------------
// K2: one block per (b, i-pair, g). Grid (28, 8, 32).
// -------------------------------------------------------------------------
__global__ __launch_bounds__(256) void attn_kernel(
    const f16* __restrict__ qt, const f16* __restrict__ kt, const f16* __restrict__ vt2,
    const float* __restrict__ q_rel, const float* __restrict__ k_rel, const float* __restrict__ v_rel,
    const float* __restrict__ g_qk, const float* __restrict__ b_qk,
    const float* __restrict__ g_qr, const float* __restrict__ b_qr,
    const float* __restrict__ g_kr, const float* __restrict__ b_kr,
    const float* __restrict__ g_sv, const float* __restrict__ b_sv,
    const float* __restrict__ g_sve, const float* __restrict__ b_sve,
    float* __restrict__ out)
{
    const int i0 = blockIdx.x * 2;   // i-pair base, 0..54
    const int g  = blockIdx.y;       // 8
    const int b  = blockIdx.z;       // 32
    const int t  = threadIdx.x;

    // s32 (raw scores, both i) is aliased by s16 (normalized sim, both i):
    // s16 needs 2*56*58*2 = 12992 B <= 25536 B. All s32 reads complete before
    // the mid-Phase-C barrier; s16 writes happen only after it.
    __shared__ float s32[2][56][57];          // 25536 B
    __shared__ f16 qi [2][56 * 8];            // sqk-scaled q rows (i0, i0+1)
    __shared__ f16 qe [2][56 * 8];            // (sqr/sqk)-scaled q_rel[i-j+55]
    __shared__ f16 ke [2][56 * 8];            // skr-scaled      k_rel[j-i+55]
    __shared__ f16 ve2[2][28 * 32];           // (gsve/gsv)-scaled v_rel, J-pair layout
    f16* const s16 = (f16*)&s32[0][0][0];     // [2][56][58] f16, aliased

    const float inv = 1.0f / sqrtf(1.001f);
    const int bg = (b * GG + g) * PLANE;

    const float sqk = g_qk[g] * inv;
    const float sqr = g_qr[g] * inv;
    const float skr = g_kr[g] * inv;
    const float r_qr = sqr / sqk;                          // folded into qe
    const float bias = b_qk[g] + b_qr[g] + b_kr[g];        // single score bias

    // ---- Phase A: stage scaled operands ----
    if (t < 112) {
        const int ii = (t >= 56) ? 1 : 0;
        const int w  = t - ii * 56;
        f16x8 v = *(const f16x8*)&qt[(size_t)(bg + (i0 + ii) * HH + w) * 8];
        #pragma unroll
        for (int c = 0; c < 8; ++c) v[c] = (f16)((float)v[c] * sqk);
        *(f16x8*)&qi[ii][w * 8] = v;
    }
    for (int idx = t; idx < 896; idx += 256) {             // 2 x 448
        const int ii = (idx >= 448) ? 1 : 0;
        const int r  = idx - ii * 448;
        const int j = r >> 3, c = r & 7;
        const int iv = i0 + ii;
        qe[ii][r] = (f16)(r_qr * q_rel[(iv - j + 55) * 8 + c]);
        ke[ii][r] = (f16)(skr  * k_rel[(j - iv + 55) * 8 + c]);
    }
    for (int idx = t; idx < 1792; idx += 256) {            // 2 x 896
        const int ii = (idx >= 896) ? 1 : 0;
        const int rr = idx - ii * 896;
        const int J = rr >> 5, r = rr & 31, c = r >> 1, jb = r & 1;
        const int ch = g * 16 + c;
        const float ratio = g_sve[ch] / g_sv[ch];
        ve2[ii][rr] = (f16)(ratio * v_rel[(2 * J + jb - (i0 + ii) + 55) * 16 + c]);
    }
    __syncthreads();

    // ---- Phase B: raw scores for BOTH i; wave = 14 j-rows, lane = w.
    //      kv loaded once per (j,w), reused for both i. 12 fdot2 chained into
    //      one accumulator seeded with the summed BN biases. ----
    {
        const int wv = t >> 6, lane = t & 63;
        const int wc = (lane < 56) ? lane : 55;            // dup lanes mirror w=55
        const f16x8 qv0 = *(const f16x8*)&qi[0][wc * 8];
        const f16x8 qv1 = *(const f16x8*)&qi[1][wc * 8];
        const f16* kbase = kt + (size_t)(bg + wv * 14 * HH + wc) * 8;
        #pragma unroll
        for (int jj = 0; jj < 14; ++jj) {
            const int j = wv * 14 + jj;
            const f16x8 kv = *(const f16x8*)(kbase + (size_t)jj * (HH * 8));
            #pragma unroll
            for (int ii = 0; ii < 2; ++ii) {
                const f16x8 qv = ii ? qv1 : qv0;
                const f16x8 ev = *(const f16x8*)&qe[ii][j * 8];   // LDS broadcast
                const f16x8 fv = *(const f16x8*)&ke[ii][j * 8];   // LDS broadcast
                float s = bias;
                #pragma unroll
                for (int c = 0; c < 4; ++c) {
                    const f16x2 kk = ((const f16x2*)&kv)[c];
                    const f16x2 qq = ((const f16x2*)&qv)[c];
                    s = __builtin_amdgcn_fdot2(qq, kk, s, false);                     // sqk*qk
                    s = __builtin_amdgcn_fdot2(qq, ((const f16x2*)&ev)[c], s, false); // sqr*qr
                    s = __builtin_amdgcn_fdot2(kk, ((const f16x2*)&fv)[c], s, false); // skr*kr
                }
                s32[ii][j][wc] = s;     // dup lanes write identical value
            }
        }
    }
    __syncthreads();

    // ---- Phase C: quad-local softmax, 448 units on 256 threads.
    //      Read+reduce into regs, barrier, then write s16 over s32. ----
    float e[2][14];
    float rs[2];
    #pragma unroll
    for (int uu = 0; uu < 2; ++uu) {
        const int u = t + uu * 256;
        if (u < 448) {
            const int ii = (u >= 224) ? 1 : 0;
            const int r  = u - ii * 224;
            const int j = r >> 2, q = r & 3, w0 = q * 14;
            float v[14];
            #pragma unroll
            for (int wi = 0; wi < 14; ++wi) v[wi] = s32[ii][j][w0 + wi];
            float mx = v[0];
            #pragma unroll
            for (int wi = 1; wi < 14; ++wi) mx = fmaxf(mx, v[wi]);
            mx = fmaxf(mx, __shfl_xor(mx, 1));
            mx = fmaxf(mx, __shfl_xor(mx, 2));
            float sum = 0.f;
            #pragma unroll
            for (int wi = 0; wi < 14; ++wi) { e[uu][wi] = __expf(v[wi] - mx); sum += e[uu][wi]; }
            sum += __shfl_xor(sum, 1);
            sum += __shfl_xor(sum, 2);
            rs[uu] = __builtin_amdgcn_rcpf(sum);
        }
    }
    __syncthreads();   // all s32 reads done; s16 may now overwrite it
    #pragma unroll
    for (int uu = 0; uu < 2; ++uu) {
        const int u = t + uu * 256;
        if (u < 448) {
            const int ii = (u >= 224) ? 1 : 0;
            const int r  = u - ii * 224;
            const int j = r >> 2, q = r & 3, w0 = q * 14;
            f16* sbase = s16 + ii * (56 * 58);
            #pragma unroll
            for (int wi = 0; wi < 14; ++wi)
                sbase[(w0 + wi) * 58 + j] = (f16)(e[uu][wi] * rs[uu]);
        }
    }
    __syncthreads();

    // ---- Phase D: sv + sve via fdot2 over j-pairs; vl shared across both i.
    //      sv and (ratio-scaled) sve chain into ONE accumulator per channel. ----
    if (t < 224) {
        const int w = t >> 2, cq = t & 3;
        const f16* vp  = vt2 + ((size_t)(b * GG + g) * NBLK * HH + w) * 32 + cq * 8;
        const f16* sp0 = s16 + w * 58;
        const f16* sp1 = s16 + 56 * 58 + w * 58;
        const f16* ep0 = &ve2[0][cq * 8];
        const f16* ep1 = &ve2[1][cq * 8];
        float acc[2][4] = {{0.f, 0.f, 0.f, 0.f}, {0.f, 0.f, 0.f, 0.f}};
        #pragma unroll
        for (int Jp = 0; Jp < 14; ++Jp) {
            const f16x4 p0 = *(const f16x4*)(sp0 + 4 * Jp);   // p[i0]   for J-pairs 2Jp,2Jp+1
            const f16x4 p1 = *(const f16x4*)(sp1 + 4 * Jp);   // p[i0+1]
            #pragma unroll
            for (int u = 0; u < 2; ++u) {
                const int j2 = 2 * Jp + u;                    // vt2 J index, 0..27
                const f16x8 vl = *(const f16x8*)(vp + (size_t)j2 * (HH * 32));  // shared
                const f16x8 el0 = *(const f16x8*)(ep0 + j2 * 32);
                const f16x8 el1 = *(const f16x8*)(ep1 + j2 * 32);
                const f16x2 pp[2] = { ((const f16x2*)&p0)[u], ((const f16x2*)&p1)[u] };
                #pragma unroll
                for (int ii = 0; ii < 2; ++ii) {
                    const f16x8 el = ii ? el1 : el0;
                    #pragma unroll
                    for (int c = 0; c < 4; ++c) {
                        acc[ii][c] = __builtin_amdgcn_fdot2(
                            pp[ii], ((const f16x2*)&el)[c], acc[ii][c], false);
                        acc[ii][c] = __builtin_amdgcn_fdot2(
                            pp[ii], ((const f16x2*)&vl)[c], acc[ii][c], false);
                    }
                }
            }
        }
        const int ch = g * 16 + cq * 4;
        const float4 gsv  = *(const float4*)(g_sv + ch);
        const float4 bsv  = *(const float4*)(b_sv + ch);
        const float4 bsve = *(const float4*)(b_sve + ch);
        #pragma unroll
        for (int ii = 0; ii < 2; ++ii) {
            float4 o;
            o.x = fmaf(gsv.x * inv, acc[ii][0], bsv.x + bsve.x);
            o.y = fmaf(gsv.y * inv, acc[ii][1], bsv.y + bsve.y);
            o.z = fmaf(gsv.z * inv, acc[ii][2], bsv.z + bsve.z);
            o.w = fmaf(gsv.w * inv, acc[ii][3], bsv.w + bsve.w);
            *(float4*)(out + ((size_t)(b * HH + i0 + ii) * HH + w) * 128 + ch) = o;
        }
    }
}

// -------------------------------------------------------------------------
extern "C" void kernel_launch(void* const* d_in, const int* in_sizes, int n_in,
                              void* d_out, int out_size, void* d_ws, size_t ws_size,
                              hipStream_t stream)
{
    const float* x     = (const float*)d_in[0];
    const float* w_q   = (const float*)d_in[1];
    const float* w_k   = (const float*)d_in[2];
    const float* w_v   = (const float*)d_in[3];
    const float* q_rel = (const float*)d_in[4];
    const float* k_rel = (const float*)d_in[5];
    const float* v_rel = (const float*)d_in[6];
    const float* g_q   = (const float*)d_in[7];
    const float* b_q   = (const float*)d_in[8];
    const float* g_k   = (const float*)d_in[9];
    const float* b_k   = (const float*)d_in[10];
    const float* g_v   = (const float*)d_in[11];
    const float* b_v   = (const float*)d_in[12];
    const float* g_qk  = (const float*)d_in[13];
    const float* b_qk  = (const float*)d_in[14];
    const float* g_qr  = (const float*)d_in[15];
    const float* b_qr  = (const float*)d_in[16];
    const float* g_kr  = (const float*)d_in[17];
    const float* b_kr  = (const float*)d_in[18];
    const float* g_sv  = (const float*)d_in[19];
    const float* b_sv  = (const float*)d_in[20];
    const float* g_sve = (const float*)d_in[21];
    const float* b_sve = (const float*)d_in[22];
    float* out = (float*)d_out;

    // workspace (f16): wt 32768 | qt/kt 6,422,528 each | vt2 12,845,056 (~51.5 MB)
    f16* wt  = (f16*)d_ws;
    f16* qt  = wt + 32768;
    f16* kt  = qt + (size_t)NB * GG * PLANE * 8;
    f16* vt2 = kt + (size_t)NB * GG * PLANE * 8;

    prep_kernel<<<16, 256, 0, stream>>>(w_q, w_k, w_v, wt);

    qkv_kernel<<<dim3((NB * PLANE) / MT, 2), 256, 0, stream>>>(
        x, wt, g_q, b_q, g_k, b_k, g_v, b_v, qt, kt, vt2);

    attn_kernel<<<dim3(28, 8, 32), 256, 0, stream>>>(
        qt, kt, vt2, q_rel, k_rel, v_rel,
        g_qk, b_qk, g_qr, b_qr, g_kr, b_kr, g_sv, b_sv, g_sve, b_sve, out);
}

// Round 2
// 280.838 us; speedup vs baseline: 1.0561x; 1.0561x over previous
//
#include <hip/hip_runtime.h>
#include <math.h>

// AxialAttention on MI355X — round 7.
// Round-6 post-mortem: i-pairing regressed (occupancy 62->41, FETCH unchanged)
// -> revert to round-5 geometry (grid 56x8x32, 6 blocks/CU).
// New in round 7 (keeps proven round-5 structure):
//  - Phase B: BN scales folded into staged operands (round-6-proven): 12 chained
//    fdot2 seeded with summed biases; no per-(j,w) fmaf/fadd.
//  - Phase D: sve half computed by MFMA (56x16x56 GEMM: A = s16[w][j],
//    B = veT[c][j] ratio-folded, K padded to 64 with zeros). vl half remapped to
//    the MFMA C-layout (lane owns c=lane&15 and 4 w-rows) so both accumulators
//    merge in-register. Phase-D fdot2 count halves; Phase-D runs on all 256 t.
//  - s16 resized to [64][72] (MFMA K-pad + 16B-aligned x8 reads); zeroed in A.
// LDS total 26,976 B -> still 6 blocks/CU.

typedef _Float16 f16;
typedef _Float16 f16x2 __attribute__((ext_vector_type(2)));
typedef _Float16 f16x4 __attribute__((ext_vector_type(4)));
typedef _Float16 f16x8 __attribute__((ext_vector_type(8)));
typedef float    f32x4 __attribute__((ext_vector_type(4)));
typedef unsigned int u32;
typedef unsigned int u32x2 __attribute__((ext_vector_type(2)));

static constexpr int NB    = 32;
static constexpr int HH    = 56;
static constexpr int CIN   = 128;
static constexpr int GG    = 8;
static constexpr int PLANE = HH * HH;     // 3136
static constexpr int MT    = 112;         // K1 M-tile (2 j-rows x 56 w)
static constexpr int NBLK  = 28;          // 3136 / 112

// -------------------------------------------------------------------------
// prep: Wt[d][k] f16, d in [0,256): 0-63 <- wq, 64-127 <- wk, 128-255 <- wv
// -------------------------------------------------------------------------
__global__ __launch_bounds__(256) void prep_kernel(
    const float* __restrict__ wq, const float* __restrict__ wk,
    const float* __restrict__ wv, f16* __restrict__ wt)
{
    const int id = blockIdx.x * 256 + threadIdx.x;   // 4096 total
    const int d = id >> 4, kc = id & 15;
    const float* src; int stride, dl;
    if (d < 64)       { src = wq; stride = 64;  dl = d; }
    else if (d < 128) { src = wk; stride = 64;  dl = d - 64; }
    else              { src = wv; stride = 128; dl = d - 128; }
    f16x8 v;
    #pragma unroll
    for (int kk = 0; kk < 8; ++kk)
        v[kk] = (f16)src[(kc * 8 + kk) * stride + dl];
    *(f16x8*)&wt[d * 128 + kc * 8] = v;
}

// -------------------------------------------------------------------------
// K1: block tile 112(M) x 128(N), K=128. Grid (896, 2): y=0 -> q|k, y=1 -> v.
// -------------------------------------------------------------------------
__global__ __launch_bounds__(256, 2) void qkv_kernel(
    const float* __restrict__ x, const f16* __restrict__ wt,
    const float* __restrict__ gq, const float* __restrict__ bq,
    const float* __restrict__ gk, const float* __restrict__ bk,
    const float* __restrict__ gv, const float* __restrict__ bv,
    f16* __restrict__ qt, f16* __restrict__ kt, f16* __restrict__ vt2)
{
    __shared__ f16 lds_a[MT * 136];     // A[m][k], later reused as C[m][d]
    __shared__ f16 lds_b[128 * 136];    // Bt[n][k]

    const int t    = threadIdx.x;
    const int nh   = blockIdx.y;
    const int b    = blockIdx.x / NBLK;
    const int B28  = blockIdx.x - b * NBLK;
    const int rem0 = B28 * MT;
    const size_t m0 = (size_t)b * PLANE + rem0;

    // ---- stage A: 112x128 f32 -> f16, coalesced float4 ----
    {
        const float4* xs = (const float4*)(x + m0 * CIN);
        #pragma unroll
        for (int it = 0; it < 14; ++it) {
            const int f = it * 256 + t;          // 3584 float4
            const int r = f >> 5, c = f & 31;
            const float4 v = xs[f];
            f16x4 p; p.x = (f16)v.x; p.y = (f16)v.y; p.z = (f16)v.z; p.w = (f16)v.w;
            *(f16x4*)&lds_a[r * 136 + c * 4] = p;
        }
    }
    // ---- stage B: pre-converted Wt, coalesced 16B ----
    #pragma unroll
    for (int it = 0; it < 8; ++it) {
        const int f = it * 256 + t;              // 2048 chunks
        const int n = f >> 4, kc = f & 15;
        *(f16x8*)&lds_b[n * 136 + kc * 8] =
            *(const f16x8*)&wt[(size_t)(nh * 128 + n) * 128 + kc * 8];
    }
    __syncthreads();

    const int lane = t & 63, wid = t >> 6;
    const int wn0 = wid * 32;
    const int ra = lane & 15, qd = lane >> 4;

    f32x4 acc[7][2];
    #pragma unroll
    for (int mt = 0; mt < 7; ++mt)
        #pragma unroll
        for (int nt = 0; nt < 2; ++nt)
            acc[mt][nt] = (f32x4){0.f, 0.f, 0.f, 0.f};

    #pragma unroll
    for (int ks = 0; ks < 4; ++ks) {
        f16x8 af[7], bf[2];
        #pragma unroll
        for (int mt = 0; mt < 7; ++mt)
            af[mt] = *(const f16x8*)&lds_a[(mt * 16 + ra) * 136 + ks * 32 + qd * 8];
        #pragma unroll
        for (int nt = 0; nt < 2; ++nt)
            bf[nt] = *(const f16x8*)&lds_b[(wn0 + nt * 16 + ra) * 136 + ks * 32 + qd * 8];
        #pragma unroll
        for (int mt = 0; mt < 7; ++mt)
            #pragma unroll
            for (int nt = 0; nt < 2; ++nt)
                acc[mt][nt] = __builtin_amdgcn_mfma_f32_16x16x32_f16(
                    af[mt], bf[nt], acc[mt][nt], 0, 0, 0);
    }
    __syncthreads();

    // ---- BN + f16, transpose via LDS (reuse lds_a as C[m][d]) ----
    f16* lds_c = lds_a;
    const float inv = 1.0f / sqrtf(1.001f);
    #pragma unroll
    for (int nt = 0; nt < 2; ++nt) {
        const int d  = wn0 + nt * 16 + ra;       // block-local col 0..127
        const int dg = nh * 128 + d;             // global col 0..255
        float scale, shift;
        if (dg < 64)       { scale = gq[dg] * inv;        shift = bq[dg]; }
        else if (dg < 128) { scale = gk[dg - 64] * inv;   shift = bk[dg - 64]; }
        else               { scale = gv[dg - 128] * inv;  shift = bv[dg - 128]; }
        #pragma unroll
        for (int mt = 0; mt < 7; ++mt)
            #pragma unroll
            for (int rg = 0; rg < 4; ++rg) {
                const int m = mt * 16 + qd * 4 + rg;
                lds_c[m * 136 + d] = (f16)fmaf(acc[mt][nt][rg], scale, shift);
            }
    }
    __syncthreads();

    if (nh == 0) {
        // q/k: 16B row stores, coalesced
        const int rl = t & 31, gs2 = t >> 5;
        #pragma unroll
        for (int it = 0; it < 4; ++it) {
            const int rem = it * 32 + rl;
            if (rem < MT) {
                #pragma unroll
                for (int half = 0; half < 2; ++half) {
                    const int gslot = half * 8 + gs2;
                    const f16x8 v = *(const f16x8*)&lds_c[rem * 136 + gslot * 8];
                    f16* dst = (gslot < 8) ? qt : kt;
                    const int g = gslot & 7;
                    *(f16x8*)&dst[((size_t)(b * GG + g) * PLANE + rem0 + rem) * 8] = v;
                }
            }
        }
    } else {
        // v -> vt2[bg][J=B28][w][c][jbit]: interleave rows w and w+56
        const int cq = t & 3, w8 = (t >> 2) & 7, g = t >> 5;
        #pragma unroll
        for (int it = 0; it < 7; ++it) {
            const int w = it * 8 + w8;
            const int doff = g * 16 + cq * 4;
            const u32x2 a  = *(const u32x2*)&lds_c[w * 136 + doff];         // j0: c0..c3
            const u32x2 bb = *(const u32x2*)&lds_c[(56 + w) * 136 + doff];  // j1: c0..c3
            uint4 o;
            o.x = __builtin_amdgcn_perm(a.x, bb.x, 0x01000504u);  // c0j0 c0j1
            o.y = __builtin_amdgcn_perm(a.x, bb.x, 0x03020706u);  // c1j0 c1j1
            o.z = __builtin_amdgcn_perm(a.y, bb.y, 0x01000504u);  // c2j0 c2j1
            o.w = __builtin_amdgcn_perm(a.y, bb.y, 0x03020706u);  // c3j0 c3j1
            const size_t base =
                (((size_t)(b * GG + g) * NBLK + B28) * HH + w) * 32 + cq * 8;
            *(uint4*)&vt2[base] = o;
        }
    }
}

// -------------------------------------------------------------------------
// K2: one block per (b, i, g). Grid (56, 8, 32).
// -------------------------------------------------------------------------
__global__ __launch_bounds__(256) void attn_kernel(
    const f16* __restrict__ qt, const f16* __restrict__ kt, const f16* __restrict__ vt2,
    const float* __restrict__ q_rel, const float* __restrict__ k_rel, const float* __restrict__ v_rel,
    const float* __restrict__ g_qk, const float* __restrict__ b_qk,
    const float* __restrict__ g_qr, const float* __restrict__ b_qr,
    const float* __restrict__ g_kr, const float* __restrict__ b_kr,
    const float* __restrict__ g_sv, const float* __restrict__ b_sv,
    const float* __restrict__ g_sve, const float* __restrict__ b_sve,
    float* __restrict__ out)
{
    const int i = blockIdx.x;   // 56
    const int g = blockIdx.y;   // 8
    const int b = blockIdx.z;   // 32
    const int t = threadIdx.x;

    __shared__ float s32[56][57];                                  // raw scores [j][w]
    __shared__ __attribute__((aligned(16))) f16 s16[64 * 72];      // sim^T [w][j], K-padded
    __shared__ __attribute__((aligned(16))) f16 qi[56 * 8];        // sqk-scaled q row
    __shared__ __attribute__((aligned(16))) f16 qe[56 * 8];        // (sqr/sqk)-scaled q_rel
    __shared__ __attribute__((aligned(16))) f16 ke[56 * 8];        // skr-scaled k_rel
    __shared__ __attribute__((aligned(16))) f16 veT[16 * 72];      // ratio-scaled VE^T [c][j]

    const float inv = 1.0f / sqrtf(1.001f);
    const int bg = (b * GG + g) * PLANE;

    const float sqk  = g_qk[g] * inv;
    const float r_qr = (g_qr[g] * inv) / sqk;                 // folded into qe
    const float skr  = g_kr[g] * inv;
    const float bias = b_qk[g] + b_qr[g] + b_kr[g];           // single score bias

    // ---- Phase A: stage scaled operands; zero s16 (MFMA K/M padding) ----
    if (t < 56) {
        f16x8 v = *(const f16x8*)&qt[(size_t)(bg + i * HH + t) * 8];
        #pragma unroll
        for (int c = 0; c < 8; ++c) v[c] = (f16)((float)v[c] * sqk);
        *(f16x8*)&qi[t * 8] = v;
    }
    for (int idx = t; idx < 448; idx += 256) {
        const int j = idx >> 3, c = idx & 7;
        qe[idx] = (f16)(r_qr * q_rel[(i - j + 55) * 8 + c]);
        ke[idx] = (f16)(skr  * k_rel[(j - i + 55) * 8 + c]);
    }
    for (int idx = t; idx < 1024; idx += 256) {                // veT[c][j], j<64
        const int c = idx >> 6, j = idx & 63;
        const int ch = g * 16 + c;
        const float ratio = g_sve[ch] / g_sv[ch];
        veT[c * 72 + j] = (j < 56)
            ? (f16)(ratio * v_rel[(j - i + 55) * 16 + c]) : (f16)0.f;
    }
    for (int idx = t; idx < 2304; idx += 256)                  // zero all of s16
        ((u32*)s16)[idx] = 0u;
    __syncthreads();

    // ---- Phase B: raw scores; wave = 14 j-rows, lane = w; 12 chained fdot2
    //      seeded with the summed BN biases (scales pre-folded in Phase A). ----
    {
        const int wv = t >> 6, lane = t & 63;
        const int wc = (lane < 56) ? lane : 55;                // dup lanes mirror w=55
        const f16x8 qv = *(const f16x8*)&qi[wc * 8];
        const f16* kbase = kt + (size_t)(bg + wv * 14 * HH + wc) * 8;
        for (int jj = 0; jj < 14; ++jj) {
            const int j = wv * 14 + jj;
            const f16x8 kv = *(const f16x8*)(kbase + (size_t)jj * (HH * 8));
            const f16x8 ev = *(const f16x8*)&qe[j * 8];        // LDS broadcast
            const f16x8 fv = *(const f16x8*)&ke[j * 8];        // LDS broadcast
            float s = bias;
            #pragma unroll
            for (int c = 0; c < 4; ++c) {
                const f16x2 kk = ((const f16x2*)&kv)[c];
                const f16x2 qq = ((const f16x2*)&qv)[c];
                s = __builtin_amdgcn_fdot2(qq, kk, s, false);                     // sqk*qk
                s = __builtin_amdgcn_fdot2(qq, ((const f16x2*)&ev)[c], s, false); // sqr*qr
                s = __builtin_amdgcn_fdot2(kk, ((const f16x2*)&fv)[c], s, false); // skr*kr
            }
            s32[j][wc] = s;     // dup lanes write identical value
        }
    }
    __syncthreads();

    // ---- Phase C: softmax over w per j-row. t<224: j=t>>2, quarter=t&3.
    //      Quad-local reductions (DPP shfl). Writes sim^T into s16[w][j]. ----
    if (t < 224) {
        const int j = t >> 2, q = t & 3;
        const int w0 = q * 14;
        float v[14];
        #pragma unroll
        for (int wi = 0; wi < 14; ++wi) v[wi] = s32[j][w0 + wi];
        float mx = v[0];
        #pragma unroll
        for (int wi = 1; wi < 14; ++wi) mx = fmaxf(mx, v[wi]);
        mx = fmaxf(mx, __shfl_xor(mx, 1));
        mx = fmaxf(mx, __shfl_xor(mx, 2));
        float e[14];
        float sum = 0.f;
        #pragma unroll
        for (int wi = 0; wi < 14; ++wi) { e[wi] = __expf(v[wi] - mx); sum += e[wi]; }
        sum += __shfl_xor(sum, 1);
        sum += __shfl_xor(sum, 2);
        const float rs = __builtin_amdgcn_rcpf(sum);
        #pragma unroll
        for (int wi = 0; wi < 14; ++wi)
            s16[(w0 + wi) * 72 + j] = (f16)(e[wi] * rs);
    }
    __syncthreads();

    // ---- Phase D: all 256 threads; MFMA C-layout mapping:
    //      lane owns channel c = lane&15 and w-rows wb..wb+3. ----
    {
        const int lane = t & 63, wid = t >> 6;
        const int c = lane & 15, qd = lane >> 4;

        // sve[w][c] = sum_j s16[w][j] * veT[c][j]  (GEMM, K=64 incl. zero pad)
        f32x4 eacc = (f32x4){0.f, 0.f, 0.f, 0.f};
        {
            const f16* arow = &s16[(wid * 16 + c) * 72];   // A row = M index (lane&15)
            const f16* brow = &veT[c * 72];                // B row = N index (lane&15)
            #pragma unroll
            for (int ks = 0; ks < 2; ++ks) {
                const f16x8 af = *(const f16x8*)&arow[ks * 32 + qd * 8];
                const f16x8 bf = *(const f16x8*)&brow[ks * 32 + qd * 8];
                eacc = __builtin_amdgcn_mfma_f32_16x16x32_f16(af, bf, eacc, 0, 0, 0);
            }
        }

        // vl part (w-diagonal, stays fdot2): acc[rg] over j-pairs
        const int wb = wid * 16 + qd * 4;
        float acc[4] = {0.f, 0.f, 0.f, 0.f};
        {
            const f16* sp[4]; const f16* vp[4];
            #pragma unroll
            for (int rg = 0; rg < 4; ++rg) {
                const int wc = (wb + rg < 56) ? (wb + rg) : 55;   // clamp (dup loads)
                sp[rg] = &s16[wc * 72];
                vp[rg] = vt2 + (size_t)(b * GG + g) * (NBLK * HH * 32) + wc * 32 + c * 2;
            }
            #pragma unroll 4
            for (int J = 0; J < 28; ++J) {
                #pragma unroll
                for (int rg = 0; rg < 4; ++rg) {
                    const f16x2 pp = *(const f16x2*)(sp[rg] + 2 * J);
                    const f16x2 vv = *(const f16x2*)(vp[rg] + (size_t)J * (HH * 32));
                    acc[rg] = __builtin_amdgcn_fdot2(pp, vv, acc[rg], false);
                }
            }
        }

        // epilogue: out = (vl + sve_scaled) * (g_sv*inv) + (b_sv + b_sve)
        const int ch = g * 16 + c;
        const float gs = g_sv[ch] * inv;
        const float bb = b_sv[ch] + b_sve[ch];
        #pragma unroll
        for (int rg = 0; rg < 4; ++rg) {
            const int w = wb + rg;
            if (w < 56)
                out[((size_t)(b * HH + i) * HH + w) * 128 + ch] =
                    fmaf(gs, acc[rg] + eacc[rg], bb);
        }
    }
}

// -------------------------------------------------------------------------
extern "C" void kernel_launch(void* const* d_in, const int* in_sizes, int n_in,
                              void* d_out, int out_size, void* d_ws, size_t ws_size,
                              hipStream_t stream)
{
    const float* x     = (const float*)d_in[0];
    const float* w_q   = (const float*)d_in[1];
    const float* w_k   = (const float*)d_in[2];
    const float* w_v   = (const float*)d_in[3];
    const float* q_rel = (const float*)d_in[4];
    const float* k_rel = (const float*)d_in[5];
    const float* v_rel = (const float*)d_in[6];
    const float* g_q   = (const float*)d_in[7];
    const float* b_q   = (const float*)d_in[8];
    const float* g_k   = (const float*)d_in[9];
    const float* b_k   = (const float*)d_in[10];
    const float* g_v   = (const float*)d_in[11];
    const float* b_v   = (const float*)d_in[12];
    const float* g_qk  = (const float*)d_in[13];
    const float* b_qk  = (const float*)d_in[14];
    const float* g_qr  = (const float*)d_in[15];
    const float* b_qr  = (const float*)d_in[16];
    const float* g_kr  = (const float*)d_in[17];
    const float* b_kr  = (const float*)d_in[18];
    const float* g_sv  = (const float*)d_in[19];
    const float* b_sv  = (const float*)d_in[20];
    const float* g_sve = (const float*)d_in[21];
    const float* b_sve = (const float*)d_in[22];
    float* out = (float*)d_out;

    // workspace (f16): wt 32768 | qt/kt 6,422,528 each | vt2 12,845,056 (~51.5 MB)
    f16* wt  = (f16*)d_ws;
    f16* qt  = wt + 32768;
    f16* kt  = qt + (size_t)NB * GG * PLANE * 8;
    f16* vt2 = kt + (size_t)NB * GG * PLANE * 8;

    prep_kernel<<<16, 256, 0, stream>>>(w_q, w_k, w_v, wt);

    qkv_kernel<<<dim3((NB * PLANE) / MT, 2), 256, 0, stream>>>(
        x, wt, g_q, b_q, g_k, b_k, g_v, b_v, qt, kt, vt2);

    attn_kernel<<<dim3(56, 8, 32), 256, 0, stream>>>(
        qt, kt, vt2, q_rel, k_rel, v_rel,
        g_qk, b_qk, g_qr, b_qr, g_kr, b_kr, g_sv, b_sv, g_sve, b_sve, out);
}